// Round 2
// baseline (409.496 us; speedup 1.0000x reference)
//
#include <hip/hip_runtime.h>
#include <hip/hip_bf16.h>

#define N_NODES 100000
#define E_NUM   1600000
#define IN_DIM  128
#define HID     64
#define NCLS    40
#define NBUCK   782      // ceil(N_NODES/128); bucket b owns nodes [b*128, b*128+128)
#define BCAP    3072     // per-bucket capacity incl. pad-to-8
#define ZROW    N_NODES  // sentinel node whose H row is all zeros
#define NTILES_M 6250    // N_NODES / 16
#define IN_BLOCKS 1563   // ceil(NTILES_M / 4)
#define PREP_BLKS 46
#define HTILE_E 4096
#define NHT     392      // 392*4096 = 1,605,632 >= E_NUM
#define SC_BLKS 1563     // scatter: 1563*1024 = 1,600,512 >= E_NUM
#define ROWS_BLKS NBUCK

typedef __attribute__((ext_vector_type(8))) short bf16x8;
typedef __attribute__((ext_vector_type(4))) float f32x4;

// bf16 helpers
static __device__ __forceinline__ float bflo(unsigned u) {
    return __uint_as_float(u << 16);
}
static __device__ __forceinline__ float bfhi(unsigned u) {
    return __uint_as_float(u & 0xFFFF0000u);
}
static __device__ __forceinline__ unsigned short f2bf(float f) {
    unsigned u = __float_as_uint(f);
    u += 0x7FFFu + ((u >> 16) & 1u);     // round-to-nearest-even
    return (unsigned short)(u >> 16);
}
static __device__ __forceinline__ unsigned pack2bf(float lo, float hi) {
    return (unsigned)f2bf(lo) | ((unsigned)f2bf(hi) << 16);
}

// ---- k_prep_hist: weights pre-swizzle + H sentinel zero + degree histogram.
// Histogram atomics are fire-and-forget (no return value -> no wait chain);
// deg[] is zeroed by hipMemsetAsync before this kernel.
__global__ __launch_bounds__(256) void k_prep_hist(
    const float* __restrict__ Win, const float* __restrict__ Wl,
    const float* __restrict__ Wc, unsigned* __restrict__ pWin,
    unsigned* __restrict__ pWl, unsigned* __restrict__ pWc,
    unsigned short* __restrict__ H0, unsigned short* __restrict__ H1,
    const int* __restrict__ ei, int* __restrict__ deg)
{
    const int t = threadIdx.x;
    if (blockIdx.x >= PREP_BLKS) {
        const int e0 = (blockIdx.x - PREP_BLKS) * HTILE_E;
        for (int k = 0; k < HTILE_E; k += 256) {
            const int e = e0 + k + t;
            if (e < E_NUM) atomicAdd(&deg[ei[E_NUM + e]], 1);
        }
        return;
    }
    if (blockIdx.x == 0 && t < 32) {
        ((unsigned*)(H0 + (size_t)ZROW * HID))[t] = 0;
        ((unsigned*)(H1 + (size_t)ZROW * HID))[t] = 0;
    }
    int i = blockIdx.x * 256 + t;
    if (i < 4096) {                       // W_in: 4 ntiles x 4 ksteps
        const int nt = i >> 10, ks = (i >> 8) & 3, ln = (i >> 2) & 63, jp = i & 3;
        const int n = nt * 16 + (ln & 15);
        const int k = ks * 32 + (ln >> 4) * 8 + jp * 2;
        pWin[i] = pack2bf(Win[k * HID + n], Win[(k + 1) * HID + n]);
    } else if (i < 10240) {               // 3 layers: 4 ntiles x 2 ksteps each
        int j = i - 4096;
        const int l = j >> 11; j &= 2047;
        const int nt = j >> 9, ks = (j >> 8) & 1, ln = (j >> 2) & 63, jp = j & 3;
        const int n = nt * 16 + (ln & 15);
        const int k = ks * 32 + (ln >> 4) * 8 + jp * 2;
        const float* w = Wl + (size_t)l * HID * HID;
        pWl[i - 4096] = pack2bf(w[k * HID + n], w[(k + 1) * HID + n]);
    } else if (i < 11776) {               // W_cls: 3 ntiles (48 cols, pad) x 2 ks
        const int j = i - 10240;
        const int nt = j >> 9, ks = (j >> 8) & 1, ln = (j >> 2) & 63, jp = j & 3;
        const int n = nt * 16 + (ln & 15);
        const int k = ks * 32 + (ln >> 4) * 8 + jp * 2;
        pWc[j] = (n < NCLS) ? pack2bf(Wc[k * NCLS + n], Wc[(k + 1) * NCLS + n]) : 0u;
    }
}

// ---- fused: blocks 0..781 build CSR row offsets (padded prefix per bucket);
// blocks 782+ do the input GEMM. rows is tiny; ingemm dominates; they overlap.
__global__ __launch_bounds__(256) void k_rows_ingemm(
    const int* __restrict__ deg, int* __restrict__ cur,
    int* __restrict__ row_start, int* __restrict__ row_end,
    int* __restrict__ srcs,
    const float* __restrict__ x, const unsigned* __restrict__ pWin,
    const float* __restrict__ b, unsigned short* __restrict__ H0)
{
    __shared__ int sc[128];
    __shared__ int scnt[128];
    const int t = threadIdx.x;

    if (blockIdx.x < ROWS_BLKS) {
        const int bk = blockIdx.x;
        const int node0 = bk << 7;
        if (t < 128) {
            const int c = deg[node0 + t];     // deg sized/zeroed to 100096
            scnt[t] = c;
            sc[t] = (c + 7) & ~7;
        }
        __syncthreads();
        for (int off = 1; off < 128; off <<= 1) {
            int a = (t < 128 && t >= off) ? sc[t - off] : 0;
            __syncthreads();
            if (t < 128) sc[t] += a;
            __syncthreads();
        }
        if (t < 128) {
            const int cnt = scnt[t];
            const int pc  = (cnt + 7) & ~7;
            const int ex  = sc[t] - pc;       // exclusive padded prefix
            const int rs  = bk * BCAP + ex;
            const int bend = (bk + 1) * BCAP;
            const int re  = min(rs + pc, bend);
            const int node = node0 + t;
            if (node < N_NODES) {
                row_start[node] = rs;
                row_end[node]   = re;
                cur[node]       = rs;
            }
            for (int i = rs + cnt; i < re; ++i) srcs[i] = ZROW;
        }
        return;
    }

    // ---------------- in_gemm block (MFMA, register-direct) ----------------
    const int blk  = blockIdx.x - ROWS_BLKS;
    const int lane = t & 63;
    const int w    = t >> 6;
    const int tile = blk * 4 + w;
    if (tile >= NTILES_M) return;
    const int quad = lane >> 4;
    const int mrow = lane & 15;
    const int gr   = tile * 16 + mrow;            // < 100000 always (N%16==0)
    const float* xr = x + (size_t)gr * IN_DIM;
    const bf16x8* pb = (const bf16x8*)pWin;

    f32x4 acc0 = {0.f, 0.f, 0.f, 0.f};
    f32x4 acc1 = {0.f, 0.f, 0.f, 0.f};
    f32x4 acc2 = {0.f, 0.f, 0.f, 0.f};
    f32x4 acc3 = {0.f, 0.f, 0.f, 0.f};
    #pragma unroll
    for (int ks = 0; ks < 4; ++ks) {
        const float4 v0 = *(const float4*)(xr + ks * 32 + quad * 8);
        const float4 v1 = *(const float4*)(xr + ks * 32 + quad * 8 + 4);
        union { unsigned u[4]; bf16x8 v; } au;
        au.u[0] = pack2bf(v0.x, v0.y);
        au.u[1] = pack2bf(v0.z, v0.w);
        au.u[2] = pack2bf(v1.x, v1.y);
        au.u[3] = pack2bf(v1.z, v1.w);
        acc0 = __builtin_amdgcn_mfma_f32_16x16x32_bf16(au.v, pb[       ks * 64 + lane], acc0, 0, 0, 0);
        acc1 = __builtin_amdgcn_mfma_f32_16x16x32_bf16(au.v, pb[256 +  ks * 64 + lane], acc1, 0, 0, 0);
        acc2 = __builtin_amdgcn_mfma_f32_16x16x32_bf16(au.v, pb[512 +  ks * 64 + lane], acc2, 0, 0, 0);
        acc3 = __builtin_amdgcn_mfma_f32_16x16x32_bf16(au.v, pb[768 +  ks * 64 + lane], acc3, 0, 0, 0);
    }

    const int colg = lane & 15;
    const int nodeb = tile * 16 + quad * 4;
    const float bv0 = b[     colg];
    const float bv1 = b[16 + colg];
    const float bv2 = b[32 + colg];
    const float bv3 = b[48 + colg];
    #pragma unroll
    for (int r = 0; r < 4; ++r) {
        const size_t ob = (size_t)(nodeb + r) * HID;
        H0[ob      + colg] = f2bf(fmaxf(acc0[r] + bv0, 0.f));
        H0[ob + 16 + colg] = f2bf(fmaxf(acc1[r] + bv1, 0.f));
        H0[ob + 32 + colg] = f2bf(fmaxf(acc2[r] + bv2, 0.f));
        H0[ob + 48 + colg] = f2bf(fmaxf(acc3[r] + bv3, 0.f));
    }
}

// ---- k_scatter: direct CSR fill. slot = atomicAdd(cur[dst]) is the only
// dependent latency; guard keeps overflow inside the owning bucket region.
__global__ __launch_bounds__(256) void k_scatter(
    const int* __restrict__ ei, int* __restrict__ cur, int* __restrict__ srcs)
{
    const int t = threadIdx.x;
    const int e0 = blockIdx.x * 1024;
    for (int k = 0; k < 1024; k += 256) {
        const int e = e0 + k + t;
        if (e < E_NUM) {
            const int src = ei[e];
            const int dst = ei[E_NUM + e];
            const int slot = atomicAdd(&cur[dst], 1);
            if (slot < ((dst >> 7) + 1) * BCAP) srcs[slot] = src;
        }
    }
}

// ---- shared gather phase: fills sup[16][36] with packed-bf16 U rows -------
// 16 lanes per node; each edge row (128 B) read as 8 lanes x dwordx4.
// Counted loops (trip count known up front) help the compiler pipeline.
static __device__ __forceinline__ void gather_tile(
    const int* __restrict__ row_start, const int* __restrict__ row_end,
    const int* __restrict__ srcs, const unsigned short* __restrict__ Hin,
    unsigned (*sup)[36], int row0, int t)
{
    const int lane = t & 63;
    const int w    = t >> 6;
    const int nd   = lane >> 4;          // node within wave's group of 4
    const int sub  = (lane >> 3) & 1;    // edge-parity subgroup
    const int fl   = lane & 7;           // 16B chunk within 128B row
    const int node = row0 + (w << 2) + nd;

    const int rs = row_start[node];
    int rem = row_end[node] - rs;        // multiple of 8 (padded with ZROW)
    if (rem < 0) rem = 0;
    int i = rs + sub;

    float a0 = 0.f, a1 = 0.f, a2 = 0.f, a3 = 0.f;
    float a4 = 0.f, a5 = 0.f, a6 = 0.f, a7 = 0.f;

#define ACC8(u) do { \
        a0 += bflo((u).x); a1 += bfhi((u).x); \
        a2 += bflo((u).y); a3 += bfhi((u).y); \
        a4 += bflo((u).z); a5 += bfhi((u).z); \
        a6 += bflo((u).w); a7 += bfhi((u).w); } while (0)

    for (int nfull = rem >> 4; nfull > 0; --nfull) {
        const int s0 = srcs[i     ], s1 = srcs[i +  2];
        const int s2 = srcs[i +  4], s3 = srcs[i +  6];
        const int s4 = srcs[i +  8], s5 = srcs[i + 10];
        const int s6 = srcs[i + 12], s7 = srcs[i + 14];
        const uint4 u0 = *(const uint4*)(Hin + (size_t)s0 * HID + 8 * fl);
        const uint4 u1 = *(const uint4*)(Hin + (size_t)s1 * HID + 8 * fl);
        const uint4 u2 = *(const uint4*)(Hin + (size_t)s2 * HID + 8 * fl);
        const uint4 u3 = *(const uint4*)(Hin + (size_t)s3 * HID + 8 * fl);
        const uint4 u4 = *(const uint4*)(Hin + (size_t)s4 * HID + 8 * fl);
        const uint4 u5 = *(const uint4*)(Hin + (size_t)s5 * HID + 8 * fl);
        const uint4 u6 = *(const uint4*)(Hin + (size_t)s6 * HID + 8 * fl);
        const uint4 u7 = *(const uint4*)(Hin + (size_t)s7 * HID + 8 * fl);
        ACC8(u0); ACC8(u1); ACC8(u2); ACC8(u3);
        ACC8(u4); ACC8(u5); ACC8(u6); ACC8(u7);
        i += 16;
    }
    if (rem & 8) {
        const int s0 = srcs[i    ], s1 = srcs[i + 2];
        const int s2 = srcs[i + 4], s3 = srcs[i + 6];
        const uint4 u0 = *(const uint4*)(Hin + (size_t)s0 * HID + 8 * fl);
        const uint4 u1 = *(const uint4*)(Hin + (size_t)s1 * HID + 8 * fl);
        const uint4 u2 = *(const uint4*)(Hin + (size_t)s2 * HID + 8 * fl);
        const uint4 u3 = *(const uint4*)(Hin + (size_t)s3 * HID + 8 * fl);
        ACC8(u0); ACC8(u1); ACC8(u2); ACC8(u3);
    }

    // reduce across the two edge-parity subgroups (xor lane bit 3)
    a0 += __shfl_xor(a0, 8, 64); a1 += __shfl_xor(a1, 8, 64);
    a2 += __shfl_xor(a2, 8, 64); a3 += __shfl_xor(a3, 8, 64);
    a4 += __shfl_xor(a4, 8, 64); a5 += __shfl_xor(a5, 8, 64);
    a6 += __shfl_xor(a6, 8, 64); a7 += __shfl_xor(a7, 8, 64);

    // add self row (h + agg)
    const uint4 us = *(const uint4*)(Hin + (size_t)node * HID + 8 * fl);
    ACC8(us);
#undef ACC8

    const int r = (w << 2) + nd;
    if (sub == 0) {
        sup[r][4 * fl    ] = pack2bf(a0, a1);
        sup[r][4 * fl + 1] = pack2bf(a2, a3);
    } else {
        sup[r][4 * fl + 2] = pack2bf(a4, a5);
        sup[r][4 * fl + 3] = pack2bf(a6, a7);
    }
}

// ------- layers 1-2: gather + MFMA layer GEMM, write bf16 Hout -------------
__global__ __launch_bounds__(256) void k_gather_gemm(
    const int* __restrict__ row_start, const int* __restrict__ row_end,
    const int* __restrict__ srcs,
    const unsigned short* __restrict__ Hin, const unsigned* __restrict__ pWl,
    const float* __restrict__ bl, unsigned short* __restrict__ Hout)
{
    __shared__ unsigned sup[16][36];
    const int t = threadIdx.x;
    const int row0 = blockIdx.x * 16;
    gather_tile(row_start, row_end, srcs, Hin, sup, row0, t);
    __syncthreads();

    const int lane = t & 63;
    const int w    = t >> 6;
    const int quad = lane >> 4;
    const int m    = lane & 15;
    const bf16x8* pb = (const bf16x8*)pWl;
    f32x4 acc = {0.f, 0.f, 0.f, 0.f};
    #pragma unroll
    for (int ks = 0; ks < 2; ++ks) {
        const bf16x8 a  = *(const bf16x8*)&sup[m][ks * 16 + quad * 4];
        const bf16x8 bb = pb[((w << 1) + ks) * 64 + lane];
        acc = __builtin_amdgcn_mfma_f32_16x16x32_bf16(a, bb, acc, 0, 0, 0);
    }
    const int jc = w * 16 + m;
    const float bv = bl[jc];
    #pragma unroll
    for (int r = 0; r < 4; ++r) {
        const int node = row0 + quad * 4 + r;
        Hout[(size_t)node * HID + jc] = f2bf(fmaxf(acc[r] + bv, 0.f));
    }
}

// ------- layer 3 + classifier fused: no H3 global round-trip ---------------
__global__ __launch_bounds__(256) void k_gather_gemm_cls(
    const int* __restrict__ row_start, const int* __restrict__ row_end,
    const int* __restrict__ srcs,
    const unsigned short* __restrict__ Hin, const unsigned* __restrict__ pWl,
    const float* __restrict__ bl, const unsigned* __restrict__ pWc,
    const float* __restrict__ bc, float* __restrict__ out)
{
    __shared__ unsigned sup[16][36];
    __shared__ unsigned short sh2[16][72];   // relu'd H3 tile, bf16
    const int t = threadIdx.x;
    const int row0 = blockIdx.x * 16;
    gather_tile(row_start, row_end, srcs, Hin, sup, row0, t);
    __syncthreads();

    const int lane = t & 63;
    const int w    = t >> 6;
    const int quad = lane >> 4;
    const int m    = lane & 15;
    const bf16x8* pb = (const bf16x8*)pWl;
    f32x4 acc = {0.f, 0.f, 0.f, 0.f};
    #pragma unroll
    for (int ks = 0; ks < 2; ++ks) {
        const bf16x8 a  = *(const bf16x8*)&sup[m][ks * 16 + quad * 4];
        const bf16x8 bb = pb[((w << 1) + ks) * 64 + lane];
        acc = __builtin_amdgcn_mfma_f32_16x16x32_bf16(a, bb, acc, 0, 0, 0);
    }
    const int jc = w * 16 + m;
    const float bv = bl[jc];
    #pragma unroll
    for (int r = 0; r < 4; ++r)
        sh2[quad * 4 + r][jc] = f2bf(fmaxf(acc[r] + bv, 0.f));
    __syncthreads();

    // classifier: waves 0-2 each compute 16 output cols (48 padded >= NCLS)
    if (w < 3) {
        const bf16x8* pbc = (const bf16x8*)pWc;
        f32x4 c = {0.f, 0.f, 0.f, 0.f};
        #pragma unroll
        for (int ks = 0; ks < 2; ++ks) {
            const bf16x8 a = *(const bf16x8*)&sh2[m][ks * 32 + quad * 8];
            c = __builtin_amdgcn_mfma_f32_16x16x32_bf16(a, pbc[(w * 2 + ks) * 64 + lane], c, 0, 0, 0);
        }
        const int col = w * 16 + m;
        if (col < NCLS) {
            const float bcv = bc[col];
            #pragma unroll
            for (int r = 0; r < 4; ++r)
                out[(size_t)(row0 + quad * 4 + r) * NCLS + col] = c[r] + bcv;
        }
    }
}

extern "C" void kernel_launch(void* const* d_in, const int* in_sizes, int n_in,
                              void* d_out, int out_size, void* d_ws, size_t ws_size,
                              hipStream_t stream)
{
    const float* x        = (const float*)d_in[0];
    const int*   ei       = (const int*)  d_in[1];
    const float* W_in     = (const float*)d_in[2];
    const float* b_in     = (const float*)d_in[3];
    const float* W_layers = (const float*)d_in[4];
    const float* b_layers = (const float*)d_in[5];
    const float* W_cls    = (const float*)d_in[6];
    const float* b_cls    = (const float*)d_in[7];
    float* out = (float*)d_out;

    // ws layout (~37 MB): H0, H1, srcs, CSR offsets, degree/cursor, weights
    unsigned short* H0 = (unsigned short*)d_ws;
    unsigned short* H1 = H0 + (size_t)(N_NODES + 1) * HID;
    int* srcs      = (int*)(H1 + (size_t)(N_NODES + 1) * HID);  // NBUCK*BCAP
    int* row_start = srcs + NBUCK * BCAP;         // 100000 (pad 100096)
    int* row_end   = row_start + 100096;
    int* deg       = row_end + 100096;
    int* cur       = deg + 100096;
    unsigned* pWin = (unsigned*)(cur + 100096);   // 4096
    unsigned* pWl  = pWin + 4096;                 // 6144 (3 layers x 2048)
    unsigned* pWc  = pWl + 6144;                  // 1536

    hipMemsetAsync(deg, 0, 100096 * sizeof(int), stream);

    k_prep_hist<<<PREP_BLKS + NHT, 256, 0, stream>>>(
        W_in, W_layers, W_cls, pWin, pWl, pWc, H0, H1, ei, deg);

    k_rows_ingemm<<<ROWS_BLKS + IN_BLOCKS, 256, 0, stream>>>(
        deg, cur, row_start, row_end, srcs, x, pWin, b_in, H0);

    k_scatter<<<SC_BLKS, 256, 0, stream>>>(ei, cur, srcs);

    const int gemm_blocks = N_NODES / 16;         // 6250 (gather)
    k_gather_gemm<<<gemm_blocks, 256, 0, stream>>>(
        row_start, row_end, srcs, H0, pWl,          b_layers,        H1);
    k_gather_gemm<<<gemm_blocks, 256, 0, stream>>>(
        row_start, row_end, srcs, H1, pWl + 2048,   b_layers + HID,  H0);
    k_gather_gemm_cls<<<gemm_blocks, 256, 0, stream>>>(
        row_start, row_end, srcs, H0, pWl + 4096,   b_layers + 2*HID,
        pWc, b_cls, out);
}

// Round 3
// 233.144 us; speedup vs baseline: 1.7564x; 1.7564x over previous
//
#include <hip/hip_runtime.h>
#include <hip/hip_bf16.h>

#define N_NODES 100000
#define E_NUM   1600000
#define IN_DIM  128
#define HID     64
#define NCLS    40
#define NBUCK   782      // ceil(N_NODES/128); bucket b owns nodes [b*128, b*128+128)
#define TILE_E  8192     // big tiles: bucket runs of ~10 slots -> write locality
#define NTILE   196      // ceil(E_NUM / TILE_E)
#define BCAP    3072     // per-bucket capacity incl. pad-to-8
#define ZROW    N_NODES  // sentinel node whose H row is all zeros
#define NTILES_M 6250    // N_NODES / 16
#define IN_BLOCKS 1563   // ceil(NTILES_M / 4)
#define PREP_BLKS 46

typedef __attribute__((ext_vector_type(8))) short bf16x8;
typedef __attribute__((ext_vector_type(4))) float f32x4;

// bf16 helpers
static __device__ __forceinline__ float bflo(unsigned u) {
    return __uint_as_float(u << 16);
}
static __device__ __forceinline__ float bfhi(unsigned u) {
    return __uint_as_float(u & 0xFFFF0000u);
}
static __device__ __forceinline__ unsigned short f2bf(float f) {
    unsigned u = __float_as_uint(f);
    u += 0x7FFFu + ((u >> 16) & 1u);     // round-to-nearest-even
    return (unsigned short)(u >> 16);
}
static __device__ __forceinline__ unsigned pack2bf(float lo, float hi) {
    return (unsigned)f2bf(lo) | ((unsigned)f2bf(hi) << 16);
}

// ---- K1: blocks 0..195 partition edges into buckets (batched loads);
//          blocks 196..241 pre-swizzle weights + zero H sentinel rows.
// Both halves depend only on raw inputs. cursor zeroed by hipMemsetAsync.
__global__ __launch_bounds__(256) void k_part_prep(
    const int* __restrict__ ei, int* __restrict__ cursor, int* __restrict__ pairs,
    const float* __restrict__ Win, const float* __restrict__ Wl,
    const float* __restrict__ Wc, unsigned* __restrict__ pWin,
    unsigned* __restrict__ pWl, unsigned* __restrict__ pWc,
    unsigned short* __restrict__ H0, unsigned short* __restrict__ H1)
{
    __shared__ int lh[NBUCK];
    __shared__ int lbase[NBUCK];
    __shared__ int lcnt[NBUCK];
    const int t = threadIdx.x;

    if (blockIdx.x < NTILE) {
        for (int i = t; i < NBUCK; i += 256) { lh[i] = 0; lcnt[i] = 0; }
        __syncthreads();
        const int e0 = blockIdx.x * TILE_E;
        // pass 1: histogram — batch 8 loads ahead of the LDS atomics
        #pragma unroll
        for (int k = 0; k < TILE_E; k += 2048) {
            int d[8];
            #pragma unroll
            for (int j = 0; j < 8; ++j) {
                const int e = e0 + k + j * 256 + t;
                d[j] = (e < E_NUM) ? ei[E_NUM + e] : -1;
            }
            #pragma unroll
            for (int j = 0; j < 8; ++j)
                if (d[j] >= 0) atomicAdd(&lh[d[j] >> 7], 1);
        }
        __syncthreads();
        for (int i = t; i < NBUCK; i += 256)
            lbase[i] = lh[i] ? atomicAdd(&cursor[i], lh[i]) : 0;
        __syncthreads();
        // pass 2: scatter — batch 4 edges (8 loads) ahead of atomic+store
        #pragma unroll
        for (int k = 0; k < TILE_E; k += 1024) {
            int s[4], d[4];
            #pragma unroll
            for (int j = 0; j < 4; ++j) {
                const int e = e0 + k + j * 256 + t;
                if (e < E_NUM) { s[j] = ei[e]; d[j] = ei[E_NUM + e]; }
                else           { s[j] = -1;    d[j] = -1; }
            }
            #pragma unroll
            for (int j = 0; j < 4; ++j) {
                if (d[j] >= 0) {
                    const int bkt = d[j] >> 7;
                    const int r   = lbase[bkt] + atomicAdd(&lcnt[bkt], 1);
                    if (r < BCAP) pairs[bkt * BCAP + r] = (s[j] << 7) | (d[j] & 127);
                }
            }
        }
        return;
    }

    // ---- prep half ----
    const int bi = blockIdx.x - NTILE;
    if (bi == 0 && t < 32) {
        ((unsigned*)(H0 + (size_t)ZROW * HID))[t] = 0;
        ((unsigned*)(H1 + (size_t)ZROW * HID))[t] = 0;
    }
    int i = bi * 256 + t;
    if (i < 4096) {                       // W_in: 4 ntiles x 4 ksteps
        const int nt = i >> 10, ks = (i >> 8) & 3, ln = (i >> 2) & 63, jp = i & 3;
        const int n = nt * 16 + (ln & 15);
        const int k = ks * 32 + (ln >> 4) * 8 + jp * 2;
        pWin[i] = pack2bf(Win[k * HID + n], Win[(k + 1) * HID + n]);
    } else if (i < 10240) {               // 3 layers: 4 ntiles x 2 ksteps each
        int j = i - 4096;
        const int l = j >> 11; j &= 2047;
        const int nt = j >> 9, ks = (j >> 8) & 1, ln = (j >> 2) & 63, jp = j & 3;
        const int n = nt * 16 + (ln & 15);
        const int k = ks * 32 + (ln >> 4) * 8 + jp * 2;
        const float* w = Wl + (size_t)l * HID * HID;
        pWl[i - 4096] = pack2bf(w[k * HID + n], w[(k + 1) * HID + n]);
    } else if (i < 11776) {               // W_cls: 3 ntiles (48 cols, pad) x 2 ks
        const int j = i - 10240;
        const int nt = j >> 9, ks = (j >> 8) & 1, ln = (j >> 2) & 63, jp = j & 3;
        const int n = nt * 16 + (ln & 15);
        const int k = ks * 32 + (ln >> 4) * 8 + jp * 2;
        pWc[j] = (n < NCLS) ? pack2bf(Wc[k * NCLS + n], Wc[(k + 1) * NCLS + n]) : 0u;
    }
}

// ---- K2: blocks 0..781 bsort (per-bucket counting sort -> padded CSR);
//          blocks 782+ input GEMM. bsort depends on partition, in_gemm on
//          prep — both satisfied by K1. They co-run (m114: time = max).
__global__ __launch_bounds__(256) void k_bsort_ingemm(
    const int* __restrict__ cursor, const int* __restrict__ pairs,
    int* __restrict__ srcs, int* __restrict__ row_start, int* __restrict__ row_end,
    const float* __restrict__ x, const unsigned* __restrict__ pWin,
    const float* __restrict__ b, unsigned short* __restrict__ H0)
{
    __shared__ int cnt[128];
    __shared__ int sc[128];
    __shared__ int cur[128];
    const int t = threadIdx.x;

    if (blockIdx.x < NBUCK) {
        const int bk = blockIdx.x;
        const int beg = bk * BCAP;
        const int n_e = min(cursor[bk], BCAP);
        if (t < 128) cnt[t] = 0;
        __syncthreads();
        // count — batch 4 loads ahead of atomics
        for (int i = t; i < n_e; i += 1024) {
            const int p0 = pairs[beg + i];
            const int p1 = (i + 256 < n_e) ? pairs[beg + i + 256] : -1;
            const int p2 = (i + 512 < n_e) ? pairs[beg + i + 512] : -1;
            const int p3 = (i + 768 < n_e) ? pairs[beg + i + 768] : -1;
            atomicAdd(&cnt[p0 & 127], 1);
            if (p1 >= 0) atomicAdd(&cnt[p1 & 127], 1);
            if (p2 >= 0) atomicAdd(&cnt[p2 & 127], 1);
            if (p3 >= 0) atomicAdd(&cnt[p3 & 127], 1);
        }
        __syncthreads();
        if (t < 128) sc[t] = (cnt[t] + 7) & ~7;
        __syncthreads();
        for (int off = 1; off < 128; off <<= 1) {
            int a = (t < 128 && t >= off) ? sc[t - off] : 0;
            __syncthreads();
            if (t < 128) sc[t] += a;
            __syncthreads();
        }
        const int node0 = bk << 7;
        if (t < 128) {
            const int pc = (cnt[t] + 7) & ~7;
            const int ex = sc[t] - pc;
            cur[t] = ex;
            const int node = node0 + t;
            if (node < N_NODES) {
                const int rs = beg + ex;
                row_start[node] = rs;
                row_end  [node] = min(rs + pc, beg + BCAP);
            }
            const int fb = beg + ex + cnt[t];
            const int fe = min(beg + ex + pc, beg + BCAP);
            for (int i = fb; i < fe; ++i) srcs[i] = ZROW;
        }
        __syncthreads();
        // scatter — batch 4 loads
        for (int i = t; i < n_e; i += 1024) {
            const int p0 = pairs[beg + i];
            const int p1 = (i + 256 < n_e) ? pairs[beg + i + 256] : -1;
            const int p2 = (i + 512 < n_e) ? pairs[beg + i + 512] : -1;
            const int p3 = (i + 768 < n_e) ? pairs[beg + i + 768] : -1;
            { const int r = atomicAdd(&cur[p0 & 127], 1); if (r < BCAP) srcs[beg + r] = p0 >> 7; }
            if (p1 >= 0) { const int r = atomicAdd(&cur[p1 & 127], 1); if (r < BCAP) srcs[beg + r] = p1 >> 7; }
            if (p2 >= 0) { const int r = atomicAdd(&cur[p2 & 127], 1); if (r < BCAP) srcs[beg + r] = p2 >> 7; }
            if (p3 >= 0) { const int r = atomicAdd(&cur[p3 & 127], 1); if (r < BCAP) srcs[beg + r] = p3 >> 7; }
        }
        return;
    }

    // ---------------- in_gemm block (MFMA, register-direct) ----------------
    const int blk  = blockIdx.x - NBUCK;
    const int lane = t & 63;
    const int w    = t >> 6;
    const int tile = blk * 4 + w;
    if (tile >= NTILES_M) return;
    const int quad = lane >> 4;
    const int mrow = lane & 15;
    const int gr   = tile * 16 + mrow;            // < 100000 always (N%16==0)
    const float* xr = x + (size_t)gr * IN_DIM;
    const bf16x8* pb = (const bf16x8*)pWin;

    f32x4 acc0 = {0.f, 0.f, 0.f, 0.f};
    f32x4 acc1 = {0.f, 0.f, 0.f, 0.f};
    f32x4 acc2 = {0.f, 0.f, 0.f, 0.f};
    f32x4 acc3 = {0.f, 0.f, 0.f, 0.f};
    #pragma unroll
    for (int ks = 0; ks < 4; ++ks) {
        const float4 v0 = *(const float4*)(xr + ks * 32 + quad * 8);
        const float4 v1 = *(const float4*)(xr + ks * 32 + quad * 8 + 4);
        union { unsigned u[4]; bf16x8 v; } au;
        au.u[0] = pack2bf(v0.x, v0.y);
        au.u[1] = pack2bf(v0.z, v0.w);
        au.u[2] = pack2bf(v1.x, v1.y);
        au.u[3] = pack2bf(v1.z, v1.w);
        acc0 = __builtin_amdgcn_mfma_f32_16x16x32_bf16(au.v, pb[       ks * 64 + lane], acc0, 0, 0, 0);
        acc1 = __builtin_amdgcn_mfma_f32_16x16x32_bf16(au.v, pb[256 +  ks * 64 + lane], acc1, 0, 0, 0);
        acc2 = __builtin_amdgcn_mfma_f32_16x16x32_bf16(au.v, pb[512 +  ks * 64 + lane], acc2, 0, 0, 0);
        acc3 = __builtin_amdgcn_mfma_f32_16x16x32_bf16(au.v, pb[768 +  ks * 64 + lane], acc3, 0, 0, 0);
    }

    const int colg = lane & 15;
    const int nodeb = tile * 16 + quad * 4;
    const float bv0 = b[     colg];
    const float bv1 = b[16 + colg];
    const float bv2 = b[32 + colg];
    const float bv3 = b[48 + colg];
    #pragma unroll
    for (int r = 0; r < 4; ++r) {
        const size_t ob = (size_t)(nodeb + r) * HID;
        H0[ob      + colg] = f2bf(fmaxf(acc0[r] + bv0, 0.f));
        H0[ob + 16 + colg] = f2bf(fmaxf(acc1[r] + bv1, 0.f));
        H0[ob + 32 + colg] = f2bf(fmaxf(acc2[r] + bv2, 0.f));
        H0[ob + 48 + colg] = f2bf(fmaxf(acc3[r] + bv3, 0.f));
    }
}

// ---- shared gather phase: fills sup[16][36] with packed-bf16 U rows -------
// 16 lanes per node (2 edge-parity subgroups x 8 chunk lanes x dwordx4).
static __device__ __forceinline__ void gather_tile(
    const int* __restrict__ row_start, const int* __restrict__ row_end,
    const int* __restrict__ srcs, const unsigned short* __restrict__ Hin,
    unsigned (*sup)[36], int row0, int t)
{
    const int lane = t & 63;
    const int w    = t >> 6;
    const int nd   = lane >> 4;          // node within wave's group of 4
    const int sub  = (lane >> 3) & 1;    // edge-parity subgroup
    const int fl   = lane & 7;           // 16B chunk within 128B row
    const int node = row0 + (w << 2) + nd;

    const int rs = row_start[node];
    int rem = row_end[node] - rs;        // multiple of 8 (padded with ZROW)
    if (rem < 0) rem = 0;
    int i = rs + sub;

    // self row: independent load, issue before the gather loop
    const uint4 us = *(const uint4*)(Hin + (size_t)node * HID + 8 * fl);

    float a0 = 0.f, a1 = 0.f, a2 = 0.f, a3 = 0.f;
    float a4 = 0.f, a5 = 0.f, a6 = 0.f, a7 = 0.f;

#define ACC8(u) do { \
        a0 += bflo((u).x); a1 += bfhi((u).x); \
        a2 += bflo((u).y); a3 += bfhi((u).y); \
        a4 += bflo((u).z); a5 += bfhi((u).z); \
        a6 += bflo((u).w); a7 += bfhi((u).w); } while (0)

    for (int nfull = rem >> 4; nfull > 0; --nfull) {
        const int s0 = srcs[i     ], s1 = srcs[i +  2];
        const int s2 = srcs[i +  4], s3 = srcs[i +  6];
        const int s4 = srcs[i +  8], s5 = srcs[i + 10];
        const int s6 = srcs[i + 12], s7 = srcs[i + 14];
        const uint4 u0 = *(const uint4*)(Hin + (size_t)s0 * HID + 8 * fl);
        const uint4 u1 = *(const uint4*)(Hin + (size_t)s1 * HID + 8 * fl);
        const uint4 u2 = *(const uint4*)(Hin + (size_t)s2 * HID + 8 * fl);
        const uint4 u3 = *(const uint4*)(Hin + (size_t)s3 * HID + 8 * fl);
        const uint4 u4 = *(const uint4*)(Hin + (size_t)s4 * HID + 8 * fl);
        const uint4 u5 = *(const uint4*)(Hin + (size_t)s5 * HID + 8 * fl);
        const uint4 u6 = *(const uint4*)(Hin + (size_t)s6 * HID + 8 * fl);
        const uint4 u7 = *(const uint4*)(Hin + (size_t)s7 * HID + 8 * fl);
        ACC8(u0); ACC8(u1); ACC8(u2); ACC8(u3);
        ACC8(u4); ACC8(u5); ACC8(u6); ACC8(u7);
        i += 16;
    }
    if (rem & 8) {
        const int s0 = srcs[i    ], s1 = srcs[i + 2];
        const int s2 = srcs[i + 4], s3 = srcs[i + 6];
        const uint4 u0 = *(const uint4*)(Hin + (size_t)s0 * HID + 8 * fl);
        const uint4 u1 = *(const uint4*)(Hin + (size_t)s1 * HID + 8 * fl);
        const uint4 u2 = *(const uint4*)(Hin + (size_t)s2 * HID + 8 * fl);
        const uint4 u3 = *(const uint4*)(Hin + (size_t)s3 * HID + 8 * fl);
        ACC8(u0); ACC8(u1); ACC8(u2); ACC8(u3);
    }

    // reduce across the two edge-parity subgroups (xor lane bit 3)
    a0 += __shfl_xor(a0, 8, 64); a1 += __shfl_xor(a1, 8, 64);
    a2 += __shfl_xor(a2, 8, 64); a3 += __shfl_xor(a3, 8, 64);
    a4 += __shfl_xor(a4, 8, 64); a5 += __shfl_xor(a5, 8, 64);
    a6 += __shfl_xor(a6, 8, 64); a7 += __shfl_xor(a7, 8, 64);

    // add self row (h + agg)
    ACC8(us);
#undef ACC8

    const int r = (w << 2) + nd;
    if (sub == 0) {
        sup[r][4 * fl    ] = pack2bf(a0, a1);
        sup[r][4 * fl + 1] = pack2bf(a2, a3);
    } else {
        sup[r][4 * fl + 2] = pack2bf(a4, a5);
        sup[r][4 * fl + 3] = pack2bf(a6, a7);
    }
}

// ------- layers 1-2: gather + MFMA layer GEMM, write bf16 Hout -------------
__global__ __launch_bounds__(256) void k_gather_gemm(
    const int* __restrict__ row_start, const int* __restrict__ row_end,
    const int* __restrict__ srcs,
    const unsigned short* __restrict__ Hin, const unsigned* __restrict__ pWl,
    const float* __restrict__ bl, unsigned short* __restrict__ Hout)
{
    __shared__ unsigned sup[16][36];
    const int t = threadIdx.x;
    const int row0 = blockIdx.x * 16;
    gather_tile(row_start, row_end, srcs, Hin, sup, row0, t);
    __syncthreads();

    const int lane = t & 63;
    const int w    = t >> 6;
    const int quad = lane >> 4;
    const int m    = lane & 15;
    const bf16x8* pb = (const bf16x8*)pWl;
    f32x4 acc = {0.f, 0.f, 0.f, 0.f};
    #pragma unroll
    for (int ks = 0; ks < 2; ++ks) {
        const bf16x8 a  = *(const bf16x8*)&sup[m][ks * 16 + quad * 4];
        const bf16x8 bb = pb[((w << 1) + ks) * 64 + lane];
        acc = __builtin_amdgcn_mfma_f32_16x16x32_bf16(a, bb, acc, 0, 0, 0);
    }
    const int jc = w * 16 + m;
    const float bv = bl[jc];
    #pragma unroll
    for (int r = 0; r < 4; ++r) {
        const int node = row0 + quad * 4 + r;
        Hout[(size_t)node * HID + jc] = f2bf(fmaxf(acc[r] + bv, 0.f));
    }
}

// ------- layer 3 + classifier fused: no H3 global round-trip ---------------
__global__ __launch_bounds__(256) void k_gather_gemm_cls(
    const int* __restrict__ row_start, const int* __restrict__ row_end,
    const int* __restrict__ srcs,
    const unsigned short* __restrict__ Hin, const unsigned* __restrict__ pWl,
    const float* __restrict__ bl, const unsigned* __restrict__ pWc,
    const float* __restrict__ bc, float* __restrict__ out)
{
    __shared__ unsigned sup[16][36];
    __shared__ unsigned short sh2[16][72];   // relu'd H3 tile, bf16
    const int t = threadIdx.x;
    const int row0 = blockIdx.x * 16;
    gather_tile(row_start, row_end, srcs, Hin, sup, row0, t);
    __syncthreads();

    const int lane = t & 63;
    const int w    = t >> 6;
    const int quad = lane >> 4;
    const int m    = lane & 15;
    const bf16x8* pb = (const bf16x8*)pWl;
    f32x4 acc = {0.f, 0.f, 0.f, 0.f};
    #pragma unroll
    for (int ks = 0; ks < 2; ++ks) {
        const bf16x8 a  = *(const bf16x8*)&sup[m][ks * 16 + quad * 4];
        const bf16x8 bb = pb[((w << 1) + ks) * 64 + lane];
        acc = __builtin_amdgcn_mfma_f32_16x16x32_bf16(a, bb, acc, 0, 0, 0);
    }
    const int jc = w * 16 + m;
    const float bv = bl[jc];
    #pragma unroll
    for (int r = 0; r < 4; ++r)
        sh2[quad * 4 + r][jc] = f2bf(fmaxf(acc[r] + bv, 0.f));
    __syncthreads();

    // classifier: waves 0-2 each compute 16 output cols (48 padded >= NCLS)
    if (w < 3) {
        const bf16x8* pbc = (const bf16x8*)pWc;
        f32x4 c = {0.f, 0.f, 0.f, 0.f};
        #pragma unroll
        for (int ks = 0; ks < 2; ++ks) {
            const bf16x8 a = *(const bf16x8*)&sh2[m][ks * 32 + quad * 8];
            c = __builtin_amdgcn_mfma_f32_16x16x32_bf16(a, pbc[(w * 2 + ks) * 64 + lane], c, 0, 0, 0);
        }
        const int col = w * 16 + m;
        if (col < NCLS) {
            const float bcv = bc[col];
            #pragma unroll
            for (int r = 0; r < 4; ++r)
                out[(size_t)(row0 + quad * 4 + r) * NCLS + col] = c[r] + bcv;
        }
    }
}

extern "C" void kernel_launch(void* const* d_in, const int* in_sizes, int n_in,
                              void* d_out, int out_size, void* d_ws, size_t ws_size,
                              hipStream_t stream)
{
    const float* x        = (const float*)d_in[0];
    const int*   ei       = (const int*)  d_in[1];
    const float* W_in     = (const float*)d_in[2];
    const float* b_in     = (const float*)d_in[3];
    const float* W_layers = (const float*)d_in[4];
    const float* b_layers = (const float*)d_in[5];
    const float* W_cls    = (const float*)d_in[6];
    const float* b_cls    = (const float*)d_in[7];
    float* out = (float*)d_out;

    // ws layout (~45.3 MB): H0, H1, build scratch, prepped weight fragments
    unsigned short* H0 = (unsigned short*)d_ws;
    unsigned short* H1 = H0 + (size_t)(N_NODES + 1) * HID;
    int* wsp       = (int*)(H1 + (size_t)(N_NODES + 1) * HID);
    int* pairs     = wsp;                         // NBUCK*BCAP = 2.40M ints
    int* srcs      = wsp + NBUCK * BCAP;          // 2.40M ints
    int* row_start = wsp + 2 * NBUCK * BCAP;      // 100000 (pad 100096)
    int* row_end   = row_start + 100096;          // 100000
    int* cursor    = row_end + 100096;            // 782 (pad 1024)
    unsigned* pWin = (unsigned*)(cursor + 1024);  // 4096
    unsigned* pWl  = pWin + 4096;                 // 6144 (3 layers x 2048)
    unsigned* pWc  = pWl + 6144;                  // 1536

    hipMemsetAsync(cursor, 0, 1024 * sizeof(int), stream);

    k_part_prep<<<NTILE + PREP_BLKS, 256, 0, stream>>>(
        ei, cursor, pairs, W_in, W_layers, W_cls, pWin, pWl, pWc, H0, H1);

    k_bsort_ingemm<<<NBUCK + IN_BLOCKS, 256, 0, stream>>>(
        cursor, pairs, srcs, row_start, row_end, x, pWin, b_in, H0);

    const int gemm_blocks = N_NODES / 16;         // 6250 (gather)
    k_gather_gemm<<<gemm_blocks, 256, 0, stream>>>(
        row_start, row_end, srcs, H0, pWl,          b_layers,        H1);
    k_gather_gemm<<<gemm_blocks, 256, 0, stream>>>(
        row_start, row_end, srcs, H1, pWl + 2048,   b_layers + HID,  H0);
    k_gather_gemm_cls<<<gemm_blocks, 256, 0, stream>>>(
        row_start, row_end, srcs, H0, pWl + 4096,   b_layers + 2*HID,
        pWc, b_cls, out);
}